// Round 21
// baseline (42.388 us; speedup 1.0000x reference)
//
#include <hip/hip_runtime.h>

// VQ-VAE codebook: z [32,64,32,32] f32 NCHW, embedding [1024,64] f32.
// Outputs (concat, f32): z_q NCHW (2097152) | indices as float (32768) | loss (1).
//
// R21: R20 (29.9us) + counted-vmcnt pipeline. __syncthreads() drains vmcnt(0),
// killing the DMA prefetch every tile (~0.8us x 8). Replace with 4-buffer
// staging + raw s_barrier + s_waitcnt vmcnt(8) (tail 4,0): prefetch stays in
// flight across barriers. Overwrite-safety: issue of tile t+4 happens after
// barrier t+1 => all waves finished computing tile t. Also: verify uses raw
// e + LDS enb (g_ep deleted), and vq_finish is fused via last-block atomic.

#define IDX_OFF 2097152
#define LOSS_OFF 2129920
#define BIGF 160.0f
#define U32INF 0xFFFFFFFFu

typedef __attribute__((ext_vector_type(8))) _Float16 f16x8;
typedef __attribute__((ext_vector_type(4))) float f32x4;

__device__ __align__(256) float g_enb[1024];         // ||e||^2 + 160
__device__ __align__(256) unsigned short g_bf[64 * 2 * 64 * 8]; // fp16 [g][f][lane][j]
__device__ float g_partial[512];
__device__ unsigned g_done;

typedef const __attribute__((address_space(1))) void* gvp;
typedef __attribute__((address_space(3))) void* lvp;

__device__ __forceinline__ void gll16(const void* g, void* l) {
    __builtin_amdgcn_global_load_lds((gvp)g, (lvp)l, 16, 0, 0);
}

__device__ __forceinline__ unsigned int min16u(unsigned int x) {
#pragma unroll
    for (int o = 1; o < 16; o <<= 1) {
        unsigned int y = __shfl_xor((int)x, o, 64);
        x = y < x ? y : x;
    }
    return x;
}

// ---------------- kernel 0: build enb + packed fp16 B-frags ----------------
// B-frag layout: group g, lane l (col=l&15, g4=l>>4):
// f=0: fp16(-2e)[g*16+col][g4*8+j]   f=1: ...[32+g4*8+j]
// g_bf[((g*2+f)*64+l)*8+j]: tile tt (8 groups) = contiguous 16KB at tt*16384B.
__global__ __launch_bounds__(256) void vq_prep(const float* __restrict__ e) {
    int lane = threadIdx.x & 63;
    int k    = blockIdx.x * 4 + (threadIdx.x >> 6);
    float v  = e[k * 64 + lane];
    float m2 = -2.0f * v;
    float s  = v * v;
#pragma unroll
    for (int o = 32; o; o >>= 1) s += __shfl_xor(s, o, 64);
    if (lane == 0) g_enb[k] = s + BIGF;
    if (blockIdx.x == 0 && threadIdx.x == 0) g_done = 0u;
    _Float16 h = (_Float16)m2;                       // v_cvt_f16_f32, RTE
    unsigned short hb = *(unsigned short*)&h;
    int g  = k >> 4, c = k & 15;
    int ch = lane >> 5, dc = lane & 31;
    int g4 = dc >> 3,  j = dc & 7;
    int l  = g4 * 16 + c;
    g_bf[(size_t)((g * 2 + ch) * 64 + l) * 8 + j] = hb;
}

// ---------------- kernel 1: fused screen + verify + epilogue + loss --------
// grid 512: 64 rows/block, 4 waves; wave w = rows w*16..w*16+15, ALL 1024
// codes (8 tiles x 8 groups; 4-buffer staging, counted vmcnt, raw barriers).
__global__ __launch_bounds__(256, 2) void vq_main(const float* __restrict__ z,
                                                  const float* __restrict__ e,
                                                  float* __restrict__ out) {
    __shared__ unsigned short bf[4][8 * 1024];   // 4 x 16 KB
    __shared__ float enb[1024];                  // 4 KB
    __shared__ int   stop[64][3];                // top-3 candidate k per row
    __shared__ unsigned long long skey[3][64];   // exact keys per slot
    __shared__ int   ishare[64];
    __shared__ float lred[4];
    __shared__ unsigned lastFlag;

    const int t    = threadIdx.x;
    const int lane = t & 63;
    const int w    = __builtin_amdgcn_readfirstlane(t >> 6);  // 0..3
    const int col  = lane & 15;
    const int g4   = lane >> 4;
    const int bid  = blockIdx.x;      // 0..511
    const int b    = bid >> 4;
    const int hw0  = (bid & 15) << 6;

    // ---- A-fragments (fp16) first; then pin vmcnt to 0 before DMA issues ----
    const float* zr = z + (size_t)b * 65536 + hw0 + (w * 16 + col);
    f16x8 zh[2];
#pragma unroll
    for (int c = 0; c < 2; ++c)
#pragma unroll
        for (int j = 0; j < 8; ++j) {
            int d = c * 32 + g4 * 8 + j;
            zh[c][j] = (_Float16)zr[(size_t)d * 1024];   // RTE
        }
    asm volatile("s_waitcnt vmcnt(0)" ::: "memory");
    __builtin_amdgcn_sched_barrier(0);

    // ---- issue enb (1 seg/wave) + tiles 0,1 (4 segs/wave each) ----
    gll16((const char*)g_enb + w * 1024 + lane * 16, (char*)enb + w * 1024);
#pragma unroll
    for (int i = 0; i < 4; ++i) {
        int seg = w * 4 + i;
        gll16((const char*)g_bf + seg * 1024 + lane * 16,
              (char*)&bf[0][0] + seg * 1024);
    }
#pragma unroll
    for (int i = 0; i < 4; ++i) {
        int seg = w * 4 + i;
        gll16((const char*)g_bf + 16384 + seg * 1024 + lane * 16,
              (char*)&bf[1][0] + seg * 1024);
    }

    unsigned int t0[4], t1[4], t2[4];
#pragma unroll
    for (int r = 0; r < 4; ++r) { t0[r] = U32INF; t1[r] = U32INF; t2[r] = U32INF; }

    // ---- k-loop: 8 tiles; one raw barrier/tile; counted vmcnt (never 0) ----
    for (int tt = 0; tt < 8; ++tt) {
        if (tt < 6) {   // issue tile tt+2 into buf[(tt+2)&3]
#pragma unroll
            for (int i = 0; i < 4; ++i) {
                int seg = w * 4 + i;
                gll16((const char*)g_bf + (tt + 2) * 16384 + seg * 1024 + lane * 16,
                      (char*)&bf[(tt + 2) & 3][0] + seg * 1024);
            }
            asm volatile("s_waitcnt vmcnt(8)" ::: "memory");  // my tile-tt segs done
        } else if (tt == 6) {
            asm volatile("s_waitcnt vmcnt(4)" ::: "memory");
        } else {
            asm volatile("s_waitcnt vmcnt(0)" ::: "memory");
        }
        __builtin_amdgcn_sched_barrier(0);
        __builtin_amdgcn_s_barrier();      // raw: no vmcnt drain
        __builtin_amdgcn_sched_barrier(0);

        const unsigned short* bfc = &bf[tt & 3][0];
#pragma unroll
        for (int gg = 0; gg < 8; ++gg) {
            const int kc = (tt * 8 + gg) * 16 + col;
            const f16x8* p = (const f16x8*)(bfc + gg * 1024);
            f16x8 eh0 = p[0 * 64 + lane];         // contiguous ds_read_b128
            f16x8 eh1 = p[1 * 64 + lane];

            f32x4 acc = {0.f, 0.f, 0.f, 0.f};
            acc = __builtin_amdgcn_mfma_f32_16x16x32_f16(zh[0], eh0, acc, 0, 0, 0);
            acc = __builtin_amdgcn_mfma_f32_16x16x32_f16(zh[1], eh1, acc, 0, 0, 0);

            float enbv = enb[kc];
#pragma unroll
            for (int r = 0; r < 4; ++r) {
                float cand = acc[r] + enbv;       // >0 -> uint order = float order
                unsigned int key = (__float_as_uint(cand) & 0xFFFFFC00u) | (unsigned)kc;
                unsigned int a0 = t0[r] < key ? t0[r] : key;   // top-3 insert: 5 ops
                unsigned int x  = t0[r] < key ? key : t0[r];
                unsigned int a1 = t1[r] < x ? t1[r] : x;
                unsigned int y  = t1[r] < x ? x : t1[r];
                unsigned int a2 = t2[r] < y ? t2[r] : y;
                t0[r] = a0; t1[r] = a1; t2[r] = a2;
            }
        }
    }

    // per row: global top-3 over the 16 cols (pop-min x3; keys unique)
#pragma unroll
    for (int r = 0; r < 4; ++r) {
        unsigned int x = t0[r], y = t1[r], zz = t2[r];
        unsigned int m1 = min16u(x);
        if (x == m1) { x = y; y = zz; zz = U32INF; }
        unsigned int m2 = min16u(x);
        if (x == m2) { x = y; }
        unsigned int m3 = min16u(x);
        int row = w * 16 + g4 * 4 + r;
        if (col == 0) {
            stop[row][0] = (int)(m1 & 1023u);
            stop[row][1] = (int)(m2 & 1023u);
            stop[row][2] = (int)(m3 & 1023u);
        }
    }
    __syncthreads();

    // ---- verify: waves 0-2 = slot; lane = row; exact fp32 via raw e + enb --
    if (w < 3) {
        int kc = stop[lane][w];
        const float* zbase = z + (size_t)b * 65536 + hw0 + lane;   // L1/L2-hot
        const float* ep    = e + (size_t)kc * 64;
        float d0 = 0.f, d1 = 0.f, d2 = 0.f, d3 = 0.f;
#pragma unroll
        for (int dq = 0; dq < 16; ++dq) {
            float4 ev = *(const float4*)(ep + dq * 4);
            d0 = fmaf(zbase[(size_t)(dq * 4 + 0) * 1024], ev.x, d0);
            d1 = fmaf(zbase[(size_t)(dq * 4 + 1) * 1024], ev.y, d1);
            d2 = fmaf(zbase[(size_t)(dq * 4 + 2) * 1024], ev.z, d2);
            d3 = fmaf(zbase[(size_t)(dq * 4 + 3) * 1024], ev.w, d3);
        }
        float dist = fmaf(-2.0f, (d0 + d1) + (d2 + d3), enb[kc]);
        skey[w][lane] = ((unsigned long long)__float_as_uint(dist) << 32) | (unsigned)kc;
    }
    __syncthreads();

    if (w == 0) {
        unsigned long long ky = skey[0][lane];
        unsigned long long k1 = skey[1][lane];
        unsigned long long k2 = skey[2][lane];
        ky = k1 < ky ? k1 : ky;
        ky = k2 < ky ? k2 : ky;         // exact min; ties -> smallest k
        int idx = (int)(ky & 0xFFFFFFFFull);
        out[IDX_OFF + bid * 64 + lane] = (float)idx;
        ishare[lane] = idx;
    }
    __syncthreads();

    // ---- epilogue: z_q (coalesced along hw) + loss partial ----
    {
        int idx = ishare[lane];
        const float*  zbase = z + (size_t)b * 65536 + hw0 + lane;
        float*        qbase = out + (size_t)b * 65536 + hw0 + lane;
        const float4* er4   = (const float4*)(e + (size_t)idx * 64) + (w << 2);

        float lsum = 0.f;
#pragma unroll
        for (int p = 0; p < 4; ++p) {
            float4 ev = er4[p];                        // gather, L2-resident
            int d = (w << 4) + (p << 2);
            float ezw[4] = {ev.x, ev.y, ev.z, ev.w};
#pragma unroll
            for (int qq = 0; qq < 4; ++qq) {
                float zv = zbase[(size_t)(d + qq) * 1024];
                float df = ezw[qq] - zv;
                lsum = fmaf(df, df, lsum);
                qbase[(size_t)(d + qq) * 1024] = ezw[qq];
            }
        }
#pragma unroll
        for (int o = 32; o; o >>= 1) lsum += __shfl_xor(lsum, o, 64);
        if (lane == 0) lred[w] = lsum;
    }
    __syncthreads();

    // ---- fused loss finish: last block reduces g_partial ----
    if (t == 0) {
        g_partial[bid] = (lred[0] + lred[1]) + (lred[2] + lred[3]);
        __threadfence();                               // release partial
        lastFlag = (atomicAdd(&g_done, 1u) == 511u);
    }
    __syncthreads();
    if (lastFlag && w == 0) {
        __threadfence();                               // acquire all partials
        float s = 0.f;
#pragma unroll
        for (int i = 0; i < 8; ++i) s += g_partial[lane * 8 + i];
#pragma unroll
        for (int o = 32; o; o >>= 1) s += __shfl_xor(s, o, 64);
        // loss = q_latent + 0.25*e_latent = 1.25 * mean((z_q - z)^2)
        if (lane == 0) out[LOSS_OFF] = s * (1.25f / 2097152.0f);
    }
}

extern "C" void kernel_launch(void* const* d_in, const int* in_sizes, int n_in,
                              void* d_out, int out_size, void* d_ws, size_t ws_size,
                              hipStream_t stream) {
    const float* z = (const float*)d_in[0];
    const float* e = (const float*)d_in[1];
    float* out = (float*)d_out;

    vq_prep<<<256, 256, 0, stream>>>(e);
    vq_main<<<512, 256, 0, stream>>>(z, e, out);
}

// Round 22
// 41.791 us; speedup vs baseline: 1.0143x; 1.0143x over previous
//
#include <hip/hip_runtime.h>

// VQ-VAE codebook: z [32,64,32,32] f32 NCHW, embedding [1024,64] f32.
// Outputs (concat, f32): z_q NCHW (2097152) | indices as float (32768) | loss (1).
//
// R22: R20 (29.9us, best) with its k-loop UNTOUCHED (R21's vmcnt/raw-barrier
// schedule-pinning regressed 12us — compiler scheduling wins, guide m141).
// Salvaged from R21: (1) g_ep deleted; exact verify = raw e rows + LDS enb,
// dist = fmaf(-2, dot, enb[kc]); (2) loss finish fused via last-block atomic
// (one fewer launch). Screen: fp16 single-term (11 mantissa bits, |err|<~0.03)
// + u32 keys (k in low-10 bits) + top-3 insert; exact fp32 re-verify of 3
// candidates -> np.argmin semantics (ties -> smallest k via u64 keys).

#define IDX_OFF 2097152
#define LOSS_OFF 2129920
#define BIGF 160.0f
#define U32INF 0xFFFFFFFFu

typedef __attribute__((ext_vector_type(8))) _Float16 f16x8;
typedef __attribute__((ext_vector_type(4))) float f32x4;

__device__ __align__(256) float g_enb[1024];         // ||e||^2 + 160
__device__ __align__(256) unsigned short g_bf[64 * 2 * 64 * 8]; // fp16 [g][f][lane][j]
__device__ float g_partial[512];
__device__ unsigned g_done;

typedef const __attribute__((address_space(1))) void* gvp;
typedef __attribute__((address_space(3))) void* lvp;

__device__ __forceinline__ void gll16(const void* g, void* l) {
    __builtin_amdgcn_global_load_lds((gvp)g, (lvp)l, 16, 0, 0);
}

__device__ __forceinline__ unsigned int min16u(unsigned int x) {
#pragma unroll
    for (int o = 1; o < 16; o <<= 1) {
        unsigned int y = __shfl_xor((int)x, o, 64);
        x = y < x ? y : x;
    }
    return x;
}

// ---------------- kernel 0: build enb + packed fp16 B-frags ----------------
// B-frag layout: group g, lane l (col=l&15, g4=l>>4):
// f=0: fp16(-2e)[g*16+col][g4*8+j]   f=1: ...[32+g4*8+j]
// g_bf[((g*2+f)*64+l)*8+j]: tile tt (8 groups) = contiguous 16KB at tt*16384B.
__global__ __launch_bounds__(256) void vq_prep(const float* __restrict__ e) {
    int lane = threadIdx.x & 63;
    int k    = blockIdx.x * 4 + (threadIdx.x >> 6);
    float v  = e[k * 64 + lane];
    float m2 = -2.0f * v;
    float s  = v * v;
#pragma unroll
    for (int o = 32; o; o >>= 1) s += __shfl_xor(s, o, 64);
    if (lane == 0) g_enb[k] = s + BIGF;
    if (blockIdx.x == 0 && threadIdx.x == 0) g_done = 0u;
    _Float16 h = (_Float16)m2;                       // v_cvt_f16_f32, RTE
    unsigned short hb = *(unsigned short*)&h;
    int g  = k >> 4, c = k & 15;
    int ch = lane >> 5, dc = lane & 31;
    int g4 = dc >> 3,  j = dc & 7;
    int l  = g4 * 16 + c;
    g_bf[(size_t)((g * 2 + ch) * 64 + l) * 8 + j] = hb;
}

// ---------------- kernel 1: fused screen + verify + epilogue + loss --------
// grid 512: 64 rows/block, 4 waves; wave w = rows w*16..w*16+15, ALL 1024
// codes (8 tiles x 8 groups, dbuf 2x16KB, compiler-scheduled __syncthreads).
__global__ __launch_bounds__(256, 2) void vq_main(const float* __restrict__ z,
                                                  const float* __restrict__ e,
                                                  float* __restrict__ out) {
    __shared__ unsigned short bf[2][8 * 1024];   // 2 x 16 KB
    __shared__ float enb[1024];                  // 4 KB
    __shared__ int   stop[64][3];                // top-3 candidate k per row
    __shared__ unsigned long long skey[3][64];   // exact keys per slot
    __shared__ int   ishare[64];
    __shared__ float lred[4];
    __shared__ unsigned lastFlag;

    const int t    = threadIdx.x;
    const int lane = t & 63;
    const int w    = __builtin_amdgcn_readfirstlane(t >> 6);  // 0..3
    const int col  = lane & 15;
    const int g4   = lane >> 4;
    const int bid  = blockIdx.x;      // 0..511
    const int b    = bid >> 4;
    const int hw0  = (bid & 15) << 6;

    // stage enb (4 KB) + B-tile 0 (16 KB, 16 segs, 4/wave); dests wave-uniform
    gll16((const char*)g_enb + w * 1024 + lane * 16, (char*)enb + w * 1024);
#pragma unroll
    for (int i = 0; i < 4; ++i) {
        int seg = w * 4 + i;                     // 0..15
        gll16((const char*)g_bf + seg * 1024 + lane * 16,
              (char*)&bf[0][0] + seg * 1024);
    }

    // A-fragments (fp16) for this wave's 16 rows (computed -> VGPR-resident)
    const float* zr = z + (size_t)b * 65536 + hw0 + (w * 16 + col);
    f16x8 zh[2];
#pragma unroll
    for (int c = 0; c < 2; ++c)
#pragma unroll
        for (int j = 0; j < 8; ++j) {
            int d = c * 32 + g4 * 8 + j;
            zh[c][j] = (_Float16)zr[(size_t)d * 1024];   // RTE
        }

    unsigned int t0[4], t1[4], t2[4];
#pragma unroll
    for (int r = 0; r < 4; ++r) { t0[r] = U32INF; t1[r] = U32INF; t2[r] = U32INF; }

    __syncthreads();   // DMA drained -> tile 0 + enb visible

    for (int tt = 0; tt < 8; ++tt) {
        const int cur = tt & 1;
        if (tt < 7) {   // prefetch next 16 KB tile (fire-and-forget DMA)
#pragma unroll
            for (int i = 0; i < 4; ++i) {
                int seg = w * 4 + i;
                gll16((const char*)g_bf + (tt + 1) * 16384 + seg * 1024 + lane * 16,
                      (char*)&bf[cur ^ 1][0] + seg * 1024);
            }
        }

        const unsigned short* bfc = &bf[cur][0];
#pragma unroll
        for (int gg = 0; gg < 8; ++gg) {
            const int kc = (tt * 8 + gg) * 16 + col;
            const f16x8* p = (const f16x8*)(bfc + gg * 1024);
            f16x8 eh0 = p[0 * 64 + lane];         // contiguous ds_read_b128
            f16x8 eh1 = p[1 * 64 + lane];

            f32x4 acc = {0.f, 0.f, 0.f, 0.f};
            acc = __builtin_amdgcn_mfma_f32_16x16x32_f16(zh[0], eh0, acc, 0, 0, 0);
            acc = __builtin_amdgcn_mfma_f32_16x16x32_f16(zh[1], eh1, acc, 0, 0, 0);

            float enbv = enb[kc];
#pragma unroll
            for (int r = 0; r < 4; ++r) {
                float cand = acc[r] + enbv;       // >0 -> uint order = float order
                unsigned int key = (__float_as_uint(cand) & 0xFFFFFC00u) | (unsigned)kc;
                unsigned int a0 = t0[r] < key ? t0[r] : key;   // top-3 insert: 5 ops
                unsigned int x  = t0[r] < key ? key : t0[r];
                unsigned int a1 = t1[r] < x ? t1[r] : x;
                unsigned int y  = t1[r] < x ? x : t1[r];
                unsigned int a2 = t2[r] < y ? t2[r] : y;
                t0[r] = a0; t1[r] = a1; t2[r] = a2;
            }
        }
        __syncthreads();   // readers done with bf[cur]; next DMA drained
    }

    // per row: global top-3 over the 16 cols (pop-min x3; keys unique)
#pragma unroll
    for (int r = 0; r < 4; ++r) {
        unsigned int x = t0[r], y = t1[r], zz = t2[r];
        unsigned int m1 = min16u(x);
        if (x == m1) { x = y; y = zz; zz = U32INF; }
        unsigned int m2 = min16u(x);
        if (x == m2) { x = y; }
        unsigned int m3 = min16u(x);
        int row = w * 16 + g4 * 4 + r;
        if (col == 0) {
            stop[row][0] = (int)(m1 & 1023u);
            stop[row][1] = (int)(m2 & 1023u);
            stop[row][2] = (int)(m3 & 1023u);
        }
    }
    __syncthreads();

    // ---- verify: waves 0-2 = slot; lane = row; exact fp32 via raw e + enb --
    if (w < 3) {
        int kc = stop[lane][w];
        const float* zbase = z + (size_t)b * 65536 + hw0 + lane;   // L1/L2-hot
        const float* ep    = e + (size_t)kc * 64;
        float d0 = 0.f, d1 = 0.f, d2 = 0.f, d3 = 0.f;
#pragma unroll
        for (int dq = 0; dq < 16; ++dq) {
            float4 ev = *(const float4*)(ep + dq * 4);
            d0 = fmaf(zbase[(size_t)(dq * 4 + 0) * 1024], ev.x, d0);
            d1 = fmaf(zbase[(size_t)(dq * 4 + 1) * 1024], ev.y, d1);
            d2 = fmaf(zbase[(size_t)(dq * 4 + 2) * 1024], ev.z, d2);
            d3 = fmaf(zbase[(size_t)(dq * 4 + 3) * 1024], ev.w, d3);
        }
        float dist = fmaf(-2.0f, (d0 + d1) + (d2 + d3), enb[kc]);
        skey[w][lane] = ((unsigned long long)__float_as_uint(dist) << 32) | (unsigned)kc;
    }
    __syncthreads();

    if (w == 0) {
        unsigned long long ky = skey[0][lane];
        unsigned long long k1 = skey[1][lane];
        unsigned long long k2 = skey[2][lane];
        ky = k1 < ky ? k1 : ky;
        ky = k2 < ky ? k2 : ky;         // exact min; ties -> smallest k
        int idx = (int)(ky & 0xFFFFFFFFull);
        out[IDX_OFF + bid * 64 + lane] = (float)idx;
        ishare[lane] = idx;
    }
    __syncthreads();

    // ---- epilogue: z_q (coalesced along hw) + loss partial ----
    {
        int idx = ishare[lane];
        const float*  zbase = z + (size_t)b * 65536 + hw0 + lane;
        float*        qbase = out + (size_t)b * 65536 + hw0 + lane;
        const float4* er4   = (const float4*)(e + (size_t)idx * 64) + (w << 2);

        float lsum = 0.f;
#pragma unroll
        for (int p = 0; p < 4; ++p) {
            float4 ev = er4[p];                        // gather, L2-resident
            int d = (w << 4) + (p << 2);
            float ezw[4] = {ev.x, ev.y, ev.z, ev.w};
#pragma unroll
            for (int qq = 0; qq < 4; ++qq) {
                float zv = zbase[(size_t)(d + qq) * 1024];
                float df = ezw[qq] - zv;
                lsum = fmaf(df, df, lsum);
                qbase[(size_t)(d + qq) * 1024] = ezw[qq];
            }
        }
#pragma unroll
        for (int o = 32; o; o >>= 1) lsum += __shfl_xor(lsum, o, 64);
        if (lane == 0) lred[w] = lsum;
    }
    __syncthreads();

    // ---- fused loss finish: last block reduces g_partial ----
    if (t == 0) {
        g_partial[bid] = (lred[0] + lred[1]) + (lred[2] + lred[3]);
        __threadfence();                               // release partial
        lastFlag = (atomicAdd(&g_done, 1u) == 511u);
    }
    __syncthreads();
    if (lastFlag && w == 0) {
        __threadfence();                               // acquire all partials
        float s = 0.f;
#pragma unroll
        for (int i = 0; i < 8; ++i) s += g_partial[lane * 8 + i];
#pragma unroll
        for (int o = 32; o; o >>= 1) s += __shfl_xor(s, o, 64);
        // loss = q_latent + 0.25*e_latent = 1.25 * mean((z_q - z)^2)
        if (lane == 0) out[LOSS_OFF] = s * (1.25f / 2097152.0f);
    }
}

extern "C" void kernel_launch(void* const* d_in, const int* in_sizes, int n_in,
                              void* d_out, int out_size, void* d_ws, size_t ws_size,
                              hipStream_t stream) {
    const float* z = (const float*)d_in[0];
    const float* e = (const float*)d_in[1];
    float* out = (float*)d_out;

    vq_prep<<<256, 256, 0, stream>>>(e);
    vq_main<<<512, 256, 0, stream>>>(z, e, out);
}

// Round 23
// 32.700 us; speedup vs baseline: 1.2963x; 1.2780x over previous
//
#include <hip/hip_runtime.h>

// VQ-VAE codebook: z [32,64,32,32] f32 NCHW, embedding [1024,64] f32.
// Outputs (concat, f32): z_q NCHW (2097152) | indices as float (32768) | loss (1).
//
// R23: revert to R20 (29.9us, session best) verbatim; single fence-free
// tweak: vq_finish launch dropped — vq_prep zeroes out[LOSS_OFF], each
// vq_main block atomicAdds its scaled loss partial (device-scope atomic,
// no threadfence). R22's A/B showed the fused last-block finish with
// __threadfence() cost ~12us (per-block L2 writeback on non-coherent XCD
// L2s) — fences per block are catastrophic; atomics are cheap.
//
// Screen: fp16 single-term (11 mantissa bits, |err|<~0.03) via 2 MFMAs/group;
// u32 keys (k in low-10 mantissa bits, bias 160) + 5-op top-3 insert;
// exact-fp32 re-verify of 3 candidates (g_ep rows) -> np.argmin semantics
// (ties -> smallest k via u64 keys). z_q + loss epilogue fused in vq_main.

#define IDX_OFF 2097152
#define LOSS_OFF 2129920
#define BIGF 160.0f
#define RL 72
#define U32INF 0xFFFFFFFFu

typedef __attribute__((ext_vector_type(8))) _Float16 f16x8;
typedef __attribute__((ext_vector_type(4))) float f32x4;

__device__ __align__(256) float g_ep[1024 * RL];     // [-2e | ||e||^2+160 | pad]
__device__ __align__(256) float g_enb[1024];         // dense ||e||^2+160
__device__ __align__(256) unsigned short g_bf[64 * 2 * 64 * 8]; // fp16 [g][f][lane][j]

typedef const __attribute__((address_space(1))) void* gvp;
typedef __attribute__((address_space(3))) void* lvp;

__device__ __forceinline__ void gll16(const void* g, void* l) {
    __builtin_amdgcn_global_load_lds((gvp)g, (lvp)l, 16, 0, 0);
}

__device__ __forceinline__ unsigned int min16u(unsigned int x) {
#pragma unroll
    for (int o = 1; o < 16; o <<= 1) {
        unsigned int y = __shfl_xor((int)x, o, 64);
        x = y < x ? y : x;
    }
    return x;
}

// ---------------- kernel 0: build e', enb, packed fp16 B-frags -------------
// B-frag layout: group g, lane l (col=l&15, g4=l>>4):
// f=0: fp16(-2e)[g*16+col][g4*8+j]   f=1: ...[32+g4*8+j]
// g_bf[((g*2+f)*64+l)*8+j]: tile tt (8 groups) = contiguous 16KB at tt*16384B.
__global__ __launch_bounds__(256) void vq_prep(const float* __restrict__ e,
                                               float* __restrict__ out) {
    int lane = threadIdx.x & 63;
    int k    = blockIdx.x * 4 + (threadIdx.x >> 6);
    float v  = e[k * 64 + lane];
    float m2 = -2.0f * v;
    float s  = v * v;
#pragma unroll
    for (int o = 32; o; o >>= 1) s += __shfl_xor(s, o, 64);
    g_ep[(size_t)k * RL + lane] = m2;
    if (lane == 0) { g_ep[(size_t)k * RL + 64] = s + BIGF; g_enb[k] = s + BIGF; }
    if (blockIdx.x == 0 && threadIdx.x == 0) out[LOSS_OFF] = 0.0f;
    _Float16 h = (_Float16)m2;                       // v_cvt_f16_f32, RTE
    unsigned short hb = *(unsigned short*)&h;
    int g  = k >> 4, c = k & 15;
    int ch = lane >> 5, dc = lane & 31;
    int g4 = dc >> 3,  j = dc & 7;
    int l  = g4 * 16 + c;
    g_bf[(size_t)((g * 2 + ch) * 64 + l) * 8 + j] = hb;
}

// ---------------- kernel 1: fused screen + verify + epilogue ---------------
// grid 512: 64 rows/block, 4 waves; wave w = rows w*16..w*16+15, ALL 1024
// codes (8 tiles x 8 groups, dbuf 2x16KB). Lane: col=lane&15, row=g4*4+r.
__global__ __launch_bounds__(256, 2) void vq_main(const float* __restrict__ z,
                                                  const float* __restrict__ e,
                                                  float* __restrict__ out) {
    __shared__ unsigned short bf[2][8 * 1024];   // 2 x 16 KB
    __shared__ float enb[1024];                  // 4 KB
    __shared__ int   stop[64][3];                // top-3 candidate k per row
    __shared__ unsigned long long skey[3][64];   // exact keys per slot
    __shared__ int   ishare[64];
    __shared__ float lred[4];

    const int t    = threadIdx.x;
    const int lane = t & 63;
    const int w    = __builtin_amdgcn_readfirstlane(t >> 6);  // 0..3
    const int col  = lane & 15;
    const int g4   = lane >> 4;
    const int bid  = blockIdx.x;      // 0..511
    const int b    = bid >> 4;
    const int hw0  = (bid & 15) << 6;

    // stage enb (4 KB) + B-tile 0 (16 KB, 16 segs, 4/wave); dests wave-uniform
    gll16((const char*)g_enb + w * 1024 + lane * 16, (char*)enb + w * 1024);
#pragma unroll
    for (int i = 0; i < 4; ++i) {
        int seg = w * 4 + i;                     // 0..15
        gll16((const char*)g_bf + seg * 1024 + lane * 16,
              (char*)&bf[0][0] + seg * 1024);
    }

    // A-fragments (fp16) for this wave's 16 rows (computed -> VGPR-resident)
    const float* zr = z + (size_t)b * 65536 + hw0 + (w * 16 + col);
    f16x8 zh[2];
#pragma unroll
    for (int c = 0; c < 2; ++c)
#pragma unroll
        for (int j = 0; j < 8; ++j) {
            int d = c * 32 + g4 * 8 + j;
            zh[c][j] = (_Float16)zr[(size_t)d * 1024];   // RTE
        }

    unsigned int t0[4], t1[4], t2[4];
#pragma unroll
    for (int r = 0; r < 4; ++r) { t0[r] = U32INF; t1[r] = U32INF; t2[r] = U32INF; }

    __syncthreads();   // DMA drained -> tile 0 + enb visible

    for (int tt = 0; tt < 8; ++tt) {
        const int cur = tt & 1;
        if (tt < 7) {   // prefetch next 16 KB tile (fire-and-forget DMA)
#pragma unroll
            for (int i = 0; i < 4; ++i) {
                int seg = w * 4 + i;
                gll16((const char*)g_bf + (tt + 1) * 16384 + seg * 1024 + lane * 16,
                      (char*)&bf[cur ^ 1][0] + seg * 1024);
            }
        }

        const unsigned short* bfc = &bf[cur][0];
#pragma unroll
        for (int gg = 0; gg < 8; ++gg) {
            const int kc = (tt * 8 + gg) * 16 + col;
            const f16x8* p = (const f16x8*)(bfc + gg * 1024);
            f16x8 eh0 = p[0 * 64 + lane];         // contiguous ds_read_b128
            f16x8 eh1 = p[1 * 64 + lane];

            f32x4 acc = {0.f, 0.f, 0.f, 0.f};
            acc = __builtin_amdgcn_mfma_f32_16x16x32_f16(zh[0], eh0, acc, 0, 0, 0);
            acc = __builtin_amdgcn_mfma_f32_16x16x32_f16(zh[1], eh1, acc, 0, 0, 0);

            float enbv = enb[kc];
#pragma unroll
            for (int r = 0; r < 4; ++r) {
                float cand = acc[r] + enbv;       // >0 -> uint order = float order
                unsigned int key = (__float_as_uint(cand) & 0xFFFFFC00u) | (unsigned)kc;
                unsigned int a0 = t0[r] < key ? t0[r] : key;   // top-3 insert: 5 ops
                unsigned int x  = t0[r] < key ? key : t0[r];
                unsigned int a1 = t1[r] < x ? t1[r] : x;
                unsigned int y  = t1[r] < x ? x : t1[r];
                unsigned int a2 = t2[r] < y ? t2[r] : y;
                t0[r] = a0; t1[r] = a1; t2[r] = a2;
            }
        }
        __syncthreads();   // readers done with bf[cur]; next DMA drained
    }

    // per row: global top-3 over the 16 cols (pop-min x3; keys unique)
#pragma unroll
    for (int r = 0; r < 4; ++r) {
        unsigned int x = t0[r], y = t1[r], zz = t2[r];
        unsigned int m1 = min16u(x);
        if (x == m1) { x = y; y = zz; zz = U32INF; }
        unsigned int m2 = min16u(x);
        if (x == m2) { x = y; }
        unsigned int m3 = min16u(x);
        int row = w * 16 + g4 * 4 + r;
        if (col == 0) {
            stop[row][0] = (int)(m1 & 1023u);
            stop[row][1] = (int)(m2 & 1023u);
            stop[row][2] = (int)(m3 & 1023u);
        }
    }
    __syncthreads();

    // ---- verify: waves 0-2 = slot; lane = row; exact fp32 re-evaluate ----
    if (w < 3) {
        int kc = stop[lane][w];
        const float* zbase = z + (size_t)b * 65536 + hw0 + lane;   // L1/L2-hot
        const float* ep    = g_ep + (size_t)kc * RL;
        float d0 = 0.f, d1 = 0.f, d2 = 0.f, d3 = 0.f;
#pragma unroll
        for (int dq = 0; dq < 16; ++dq) {
            float4 ev = *(const float4*)(ep + dq * 4);
            d0 = fmaf(zbase[(size_t)(dq * 4 + 0) * 1024], ev.x, d0);
            d1 = fmaf(zbase[(size_t)(dq * 4 + 1) * 1024], ev.y, d1);
            d2 = fmaf(zbase[(size_t)(dq * 4 + 2) * 1024], ev.z, d2);
            d3 = fmaf(zbase[(size_t)(dq * 4 + 3) * 1024], ev.w, d3);
        }
        float dist = (d0 + d1) + (d2 + d3) + ep[64];
        skey[w][lane] = ((unsigned long long)__float_as_uint(dist) << 32) | (unsigned)kc;
    }
    __syncthreads();

    if (w == 0) {
        unsigned long long ky = skey[0][lane];
        unsigned long long k1 = skey[1][lane];
        unsigned long long k2 = skey[2][lane];
        ky = k1 < ky ? k1 : ky;
        ky = k2 < ky ? k2 : ky;         // exact min; ties -> smallest k
        int idx = (int)(ky & 0xFFFFFFFFull);
        out[IDX_OFF + bid * 64 + lane] = (float)idx;
        ishare[lane] = idx;
    }
    __syncthreads();

    // ---- epilogue: z_q (coalesced along hw) + loss partial ----
    {
        int idx = ishare[lane];
        const float*  zbase = z + (size_t)b * 65536 + hw0 + lane;
        float*        qbase = out + (size_t)b * 65536 + hw0 + lane;
        const float4* er4   = (const float4*)(e + (size_t)idx * 64) + (w << 2);

        float lsum = 0.f;
#pragma unroll
        for (int p = 0; p < 4; ++p) {
            float4 ev = er4[p];                        // gather, L2-resident
            int d = (w << 4) + (p << 2);
            float ezw[4] = {ev.x, ev.y, ev.z, ev.w};
#pragma unroll
            for (int qq = 0; qq < 4; ++qq) {
                float zv = zbase[(size_t)(d + qq) * 1024];
                float df = ezw[qq] - zv;
                lsum = fmaf(df, df, lsum);
                qbase[(size_t)(d + qq) * 1024] = ezw[qq];
            }
        }
#pragma unroll
        for (int o = 32; o; o >>= 1) lsum += __shfl_xor(lsum, o, 64);
        if (lane == 0) lred[w] = lsum;
    }
    __syncthreads();
    // loss = q_latent + 0.25*e_latent = 1.25 * mean((z_q - z)^2); one atomic
    // per block (device-scope, no fence needed); out[LOSS_OFF] zeroed by prep.
    if (t == 0) {
        float s = (lred[0] + lred[1]) + (lred[2] + lred[3]);
        atomicAdd(out + LOSS_OFF, s * (1.25f / 2097152.0f));
    }
}

extern "C" void kernel_launch(void* const* d_in, const int* in_sizes, int n_in,
                              void* d_out, int out_size, void* d_ws, size_t ws_size,
                              hipStream_t stream) {
    const float* z = (const float*)d_in[0];
    const float* e = (const float*)d_in[1];
    float* out = (float*)d_out;

    vq_prep<<<256, 256, 0, stream>>>(e, out);
    vq_main<<<512, 256, 0, stream>>>(z, e, out);
}

// Round 24
// 29.984 us; speedup vs baseline: 1.4137x; 1.0906x over previous
//
#include <hip/hip_runtime.h>

// VQ-VAE codebook: z [32,64,32,32] f32 NCHW, embedding [1024,64] f32.
// Outputs (concat, f32): z_q NCHW (2097152) | indices as float (32768) | loss (1).
//
// FINAL (R20, session best: 29.9us total, passed, absmax 2e-3).
// Architecture: fp16 single-term MFMA screen + exact fp32 re-verify.
//   d~ = fp16(z).fp16(-2e) + ||e||^2+160 (fp16: 11 mantissa bits, |err|<~0.03)
//   screened per-row top-3 (u32 keys, k packed in low-10 mantissa bits),
//   then 3 candidates re-evaluated in exact fp32 -> indices match np.argmin
//   exactly (ties -> smallest k via u64 key min). z_q + loss fused in-kernel.
// Delivery (the hard-won part): B-fragments pre-packed in lane order by prep,
// staged via wave-uniform-dest global_load_lds (linear, conflict-free),
// double-buffered 16KB tiles, compiler-scheduled __syncthreads k-loop.
// Session lessons: loaded-value reg arrays get demoted (LDS staging is the
// only reliable operand path); barrier count costs ~0.8us each; occupancy is
// structurally capped at 2 waves/SIMD; schedule-pinning asm and per-block
// threadfence both regress heavily.

#define IDX_OFF 2097152
#define LOSS_OFF 2129920
#define BIGF 160.0f
#define RL 72
#define U32INF 0xFFFFFFFFu

typedef __attribute__((ext_vector_type(8))) _Float16 f16x8;
typedef __attribute__((ext_vector_type(4))) float f32x4;

__device__ __align__(256) float g_ep[1024 * RL];     // [-2e | ||e||^2+160 | pad]
__device__ __align__(256) float g_enb[1024];         // dense ||e||^2+160
__device__ __align__(256) unsigned short g_bf[64 * 2 * 64 * 8]; // fp16 [g][f][lane][j]
__device__ float g_partial[512];

typedef const __attribute__((address_space(1))) void* gvp;
typedef __attribute__((address_space(3))) void* lvp;

__device__ __forceinline__ void gll16(const void* g, void* l) {
    __builtin_amdgcn_global_load_lds((gvp)g, (lvp)l, 16, 0, 0);
}

__device__ __forceinline__ unsigned int min16u(unsigned int x) {
#pragma unroll
    for (int o = 1; o < 16; o <<= 1) {
        unsigned int y = __shfl_xor((int)x, o, 64);
        x = y < x ? y : x;
    }
    return x;
}

// ---------------- kernel 0: build e', enb, packed fp16 B-frags -------------
// B-frag layout: group g, lane l (col=l&15, g4=l>>4):
// f=0: fp16(-2e)[g*16+col][g4*8+j]   f=1: ...[32+g4*8+j]
// g_bf[((g*2+f)*64+l)*8+j]: tile tt (8 groups) = contiguous 16KB at tt*16384B.
__global__ __launch_bounds__(256) void vq_prep(const float* __restrict__ e) {
    int lane = threadIdx.x & 63;
    int k    = blockIdx.x * 4 + (threadIdx.x >> 6);
    float v  = e[k * 64 + lane];
    float m2 = -2.0f * v;
    float s  = v * v;
#pragma unroll
    for (int o = 32; o; o >>= 1) s += __shfl_xor(s, o, 64);
    g_ep[(size_t)k * RL + lane] = m2;
    if (lane == 0) { g_ep[(size_t)k * RL + 64] = s + BIGF; g_enb[k] = s + BIGF; }
    _Float16 h = (_Float16)m2;                       // v_cvt_f16_f32, RTE
    unsigned short hb = *(unsigned short*)&h;
    int g  = k >> 4, c = k & 15;
    int ch = lane >> 5, dc = lane & 31;
    int g4 = dc >> 3,  j = dc & 7;
    int l  = g4 * 16 + c;
    g_bf[(size_t)((g * 2 + ch) * 64 + l) * 8 + j] = hb;
}

// ---------------- kernel 1: fused screen + verify + epilogue ---------------
// grid 512: 64 rows/block, 4 waves; wave w = rows w*16..w*16+15, ALL 1024
// codes (8 tiles x 8 groups, dbuf 2x16KB). Lane: col=lane&15, row=g4*4+r.
__global__ __launch_bounds__(256, 2) void vq_main(const float* __restrict__ z,
                                                  const float* __restrict__ e,
                                                  float* __restrict__ out) {
    __shared__ unsigned short bf[2][8 * 1024];   // 2 x 16 KB
    __shared__ float enb[1024];                  // 4 KB
    __shared__ int   stop[64][3];                // top-3 candidate k per row
    __shared__ unsigned long long skey[3][64];   // exact keys per slot
    __shared__ int   ishare[64];
    __shared__ float lred[4];

    const int t    = threadIdx.x;
    const int lane = t & 63;
    const int w    = __builtin_amdgcn_readfirstlane(t >> 6);  // 0..3
    const int col  = lane & 15;
    const int g4   = lane >> 4;
    const int bid  = blockIdx.x;      // 0..511
    const int b    = bid >> 4;
    const int hw0  = (bid & 15) << 6;

    // stage enb (4 KB) + B-tile 0 (16 KB, 16 segs, 4/wave); dests wave-uniform
    gll16((const char*)g_enb + w * 1024 + lane * 16, (char*)enb + w * 1024);
#pragma unroll
    for (int i = 0; i < 4; ++i) {
        int seg = w * 4 + i;                     // 0..15
        gll16((const char*)g_bf + seg * 1024 + lane * 16,
              (char*)&bf[0][0] + seg * 1024);
    }

    // A-fragments (fp16) for this wave's 16 rows (computed -> VGPR-resident)
    const float* zr = z + (size_t)b * 65536 + hw0 + (w * 16 + col);
    f16x8 zh[2];
#pragma unroll
    for (int c = 0; c < 2; ++c)
#pragma unroll
        for (int j = 0; j < 8; ++j) {
            int d = c * 32 + g4 * 8 + j;
            zh[c][j] = (_Float16)zr[(size_t)d * 1024];   // RTE
        }

    unsigned int t0[4], t1[4], t2[4];
#pragma unroll
    for (int r = 0; r < 4; ++r) { t0[r] = U32INF; t1[r] = U32INF; t2[r] = U32INF; }

    __syncthreads();   // DMA drained -> tile 0 + enb visible

    for (int tt = 0; tt < 8; ++tt) {
        const int cur = tt & 1;
        if (tt < 7) {   // prefetch next 16 KB tile (fire-and-forget DMA)
#pragma unroll
            for (int i = 0; i < 4; ++i) {
                int seg = w * 4 + i;
                gll16((const char*)g_bf + (tt + 1) * 16384 + seg * 1024 + lane * 16,
                      (char*)&bf[cur ^ 1][0] + seg * 1024);
            }
        }

        const unsigned short* bfc = &bf[cur][0];
#pragma unroll
        for (int gg = 0; gg < 8; ++gg) {
            const int kc = (tt * 8 + gg) * 16 + col;
            const f16x8* p = (const f16x8*)(bfc + gg * 1024);
            f16x8 eh0 = p[0 * 64 + lane];         // contiguous ds_read_b128
            f16x8 eh1 = p[1 * 64 + lane];

            f32x4 acc = {0.f, 0.f, 0.f, 0.f};
            acc = __builtin_amdgcn_mfma_f32_16x16x32_f16(zh[0], eh0, acc, 0, 0, 0);
            acc = __builtin_amdgcn_mfma_f32_16x16x32_f16(zh[1], eh1, acc, 0, 0, 0);

            float enbv = enb[kc];
#pragma unroll
            for (int r = 0; r < 4; ++r) {
                float cand = acc[r] + enbv;       // >0 -> uint order = float order
                unsigned int key = (__float_as_uint(cand) & 0xFFFFFC00u) | (unsigned)kc;
                unsigned int a0 = t0[r] < key ? t0[r] : key;   // top-3 insert: 5 ops
                unsigned int x  = t0[r] < key ? key : t0[r];
                unsigned int a1 = t1[r] < x ? t1[r] : x;
                unsigned int y  = t1[r] < x ? x : t1[r];
                unsigned int a2 = t2[r] < y ? t2[r] : y;
                t0[r] = a0; t1[r] = a1; t2[r] = a2;
            }
        }
        __syncthreads();   // readers done with bf[cur]; next DMA drained
    }

    // per row: global top-3 over the 16 cols (pop-min x3; keys unique)
#pragma unroll
    for (int r = 0; r < 4; ++r) {
        unsigned int x = t0[r], y = t1[r], zz = t2[r];
        unsigned int m1 = min16u(x);
        if (x == m1) { x = y; y = zz; zz = U32INF; }
        unsigned int m2 = min16u(x);
        if (x == m2) { x = y; }
        unsigned int m3 = min16u(x);
        int row = w * 16 + g4 * 4 + r;
        if (col == 0) {
            stop[row][0] = (int)(m1 & 1023u);
            stop[row][1] = (int)(m2 & 1023u);
            stop[row][2] = (int)(m3 & 1023u);
        }
    }
    __syncthreads();

    // ---- verify: waves 0-2 = slot; lane = row; exact fp32 re-evaluate ----
    if (w < 3) {
        int kc = stop[lane][w];
        const float* zbase = z + (size_t)b * 65536 + hw0 + lane;   // L1/L2-hot
        const float* ep    = g_ep + (size_t)kc * RL;
        float d0 = 0.f, d1 = 0.f, d2 = 0.f, d3 = 0.f;
#pragma unroll
        for (int dq = 0; dq < 16; ++dq) {
            float4 ev = *(const float4*)(ep + dq * 4);
            d0 = fmaf(zbase[(size_t)(dq * 4 + 0) * 1024], ev.x, d0);
            d1 = fmaf(zbase[(size_t)(dq * 4 + 1) * 1024], ev.y, d1);
            d2 = fmaf(zbase[(size_t)(dq * 4 + 2) * 1024], ev.z, d2);
            d3 = fmaf(zbase[(size_t)(dq * 4 + 3) * 1024], ev.w, d3);
        }
        float dist = (d0 + d1) + (d2 + d3) + ep[64];
        skey[w][lane] = ((unsigned long long)__float_as_uint(dist) << 32) | (unsigned)kc;
    }
    __syncthreads();

    if (w == 0) {
        unsigned long long ky = skey[0][lane];
        unsigned long long k1 = skey[1][lane];
        unsigned long long k2 = skey[2][lane];
        ky = k1 < ky ? k1 : ky;
        ky = k2 < ky ? k2 : ky;         // exact min; ties -> smallest k
        int idx = (int)(ky & 0xFFFFFFFFull);
        out[IDX_OFF + bid * 64 + lane] = (float)idx;
        ishare[lane] = idx;
    }
    __syncthreads();

    // ---- epilogue: z_q (coalesced along hw) + loss partial ----
    {
        int idx = ishare[lane];
        const float*  zbase = z + (size_t)b * 65536 + hw0 + lane;
        float*        qbase = out + (size_t)b * 65536 + hw0 + lane;
        const float4* er4   = (const float4*)(e + (size_t)idx * 64) + (w << 2);

        float lsum = 0.f;
#pragma unroll
        for (int p = 0; p < 4; ++p) {
            float4 ev = er4[p];                        // gather, L2-resident
            int d = (w << 4) + (p << 2);
            float ezw[4] = {ev.x, ev.y, ev.z, ev.w};
#pragma unroll
            for (int qq = 0; qq < 4; ++qq) {
                float zv = zbase[(size_t)(d + qq) * 1024];
                float df = ezw[qq] - zv;
                lsum = fmaf(df, df, lsum);
                qbase[(size_t)(d + qq) * 1024] = ezw[qq];
            }
        }
#pragma unroll
        for (int o = 32; o; o >>= 1) lsum += __shfl_xor(lsum, o, 64);
        if (lane == 0) lred[w] = lsum;
    }
    __syncthreads();
    if (t == 0)
        g_partial[bid] = (lred[0] + lred[1]) + (lred[2] + lred[3]);
}

// ---------------- kernel 2: loss scalar ------------------------------------
__global__ __launch_bounds__(64) void vq_finish(float* __restrict__ out) {
    int lane = threadIdx.x;
    float s = 0.f;
#pragma unroll
    for (int i = 0; i < 8; ++i) s += g_partial[lane * 8 + i];
#pragma unroll
    for (int o = 32; o; o >>= 1) s += __shfl_xor(s, o, 64);
    // loss = q_latent + 0.25*e_latent = 1.25 * mean((z_q - z)^2)
    if (lane == 0) out[LOSS_OFF] = s * (1.25f / 2097152.0f);
}

extern "C" void kernel_launch(void* const* d_in, const int* in_sizes, int n_in,
                              void* d_out, int out_size, void* d_ws, size_t ws_size,
                              hipStream_t stream) {
    const float* z = (const float*)d_in[0];
    const float* e = (const float*)d_in[1];
    float* out = (float*)d_out;

    vq_prep<<<256, 256, 0, stream>>>(e);
    vq_main<<<512, 256, 0, stream>>>(z, e, out);
    vq_finish<<<1, 64, 0, stream>>>(out);
}